// Round 12
// baseline (200.151 us; speedup 1.0000x reference)
//
#include <hip/hip_runtime.h>

#define NB 4096
#define NT 512
#define HS 42   // ushort stride per batch row = 21 dwords (ODD): 21n mod 32 is
                // injective over n=0..15 -> h-fragment reads are <=2-way (free);
                // rows only 4B-aligned -> fragment loads are 4x ds_read_b32

typedef float f32x4 __attribute__((ext_vector_type(4)));
typedef short bf16x8 __attribute__((ext_vector_type(8)));
typedef unsigned uint32x4 __attribute__((ext_vector_type(4)));

#define L2E  1.4426950408889634f   // log2(e)
#define L2E2 2.8853900817779268f   // 2*log2(e)

// ocml native exp2 -> single v_exp_f32, compiler-visible (no inline asm)
extern "C" __device__ float __ocml_native_exp2_f32(float);
__device__ __forceinline__ float ex2(float x) { return __ocml_native_exp2_f32(x); }

__device__ __forceinline__ float frcp(float x) { return __builtin_amdgcn_rcpf(x); }
__device__ __forceinline__ float ftanh(float x) {   // off-chain users only
    return 2.0f * frcp(1.0f + __expf(-2.0f * x)) - 1.0f;
}
// one inst packs two f32->bf16 (RTNE): result = [bf16(a) | bf16(b)<<16]
__device__ __forceinline__ unsigned cvt_pk_bf16(float a, float b) {
    unsigned r;
    asm("v_cvt_pk_bf16_f32 %0, %1, %2" : "=v"(r) : "v"(a), "v"(b));
    return r;
}
// RTNE f32->bf16 (prologue / weight prep only)
__device__ __forceinline__ unsigned short f2bf(float f) {
    unsigned u = __builtin_bit_cast(unsigned, f);
    u += 0x7fffu + ((u >> 16) & 1u);
    return (unsigned short)(u >> 16);
}
__device__ __forceinline__ float bf2f(unsigned short h) {
    return __builtin_bit_cast(float, (unsigned)h << 16);
}
// 16B fragment from a 4B-aligned LDS address: 4x ds_read_b32
__device__ __forceinline__ bf16x8 ld_frag4(const unsigned short* p) {
    const unsigned* q = (const unsigned*)p;
    uint32x4 u = {q[0], q[1], q[2], q[3]};
    return __builtin_bit_cast(bf16x8, u);
}

// 256 blocks x 8 waves x 16 batches (R11 structure; only the LDS stride
// changed 40->42). Per step, wave w computes its 16-row gate tile with ONE
// mfma_f32_16x16x32_bf16 (A = permuted W_hh prescaled by -log2e / -2log2e,
// B = h bf16); C/D layout (col=lane&15=batch n, row-group=lane>>4=g) gives
// each lane all 4 gates of hidden j=4*wid+g -> activations in-register, one
// barrier/step; every exp is a bare exp2 (ctilm = -2log2e*c). Chain:
// bar -> 4x ds_read_b32 (conflict-free banks) -> MFMA -> 5 exp2 + 3 rcp ->
// b16 write -> bar. tanh(h), sh_t write and the chunked head (hi/lo W1 MFMA
// pair per 8 steps) run post-barrier in the next step's read/MFMA shadow.
__global__ __launch_bounds__(512, 2) void lstm_mfma_kernel(
    const float* __restrict__ x,
    const float* __restrict__ W_ih,
    const float* __restrict__ W_hh,
    const float* __restrict__ b_ih,
    const float* __restrict__ b_hh,
    const float* __restrict__ W1,
    const float* __restrict__ b1,
    const float* __restrict__ W2,
    const float* __restrict__ b2,
    float* __restrict__ out)
{
    const int tid  = threadIdx.x;
    const int wid  = tid >> 6;
    const int lane = tid & 63;
    const int g    = lane >> 4;     // row-group (C rows 4g..4g+3) / B k-slice
    const int n    = lane & 15;     // batch column
    const int j    = 4 * wid + g;   // hidden unit owned by this lane
    const int batch0 = blockIdx.x * 16;

    __shared__ __align__(16) unsigned short sh_h[2][16][HS];    // h bf16 [buf][n][j]
    __shared__ __align__(16) unsigned short sh_t[2][8][16][HS]; // tanh(h) [buf][tc][n][j]

    // ---- gate A fragment: lane holds row m=lane&15, k = 8g..8g+7 of the
    //      permuted W_hh tile (row m -> gate (m&3), hidden 4*wid+(m>>2)),
    //      prescaled by -log2e (g-gate row: -2log2e) ----
    bf16x8 afrag;
    {
        const int m = lane & 15;
        const float nsc = ((m & 3) == 2) ? -L2E2 : -L2E;
        const int grow = (m & 3) * 32 + 4 * wid + (m >> 2);
        const float* wp = W_hh + grow * 32 + 8 * g;
#pragma unroll
        for (int i = 0; i < 8; ++i) afrag[i] = (short)f2bf(wp[i] * nsc);
    }

    // ---- per-lane gate params for hidden j: rows r*32+j, prescaled ----
    float wihx[4], wihy[4], bias[4];
#pragma unroll
    for (int r = 0; r < 4; ++r) {
        const float nsc = (r == 2) ? -L2E2 : -L2E;
        const int row = r * 32 + j;
        wihx[r] = W_ih[row * 2 + 0] * nsc;
        wihy[r] = W_ih[row * 2 + 1] * nsc;
        bias[r] = (b_ih[row] + b_hh[row]) * nsc;
    }

    // ---- head A fragment: W1 rows m=lane&15, split bf16 hi+lo (unscaled) ----
    bf16x8 w1hi, w1lo;
    {
        const float* wp = W1 + (lane & 15) * 32 + 8 * g;
#pragma unroll
        for (int i = 0; i < 8; ++i) {
            const float w = wp[i];
            const unsigned short hi = f2bf(w);
            w1hi[i] = (short)hi;
            w1lo[i] = (short)f2bf(w - bf2f(hi));
        }
    }
    float b1r[4], w2r[4];   // fc1 output d = 4g+r
#pragma unroll
    for (int r = 0; r < 4; ++r) {
        b1r[r] = b1[4 * g + r];
        w2r[r] = W2[4 * g + r];
    }
    const float b2v = b2[0];

    // ---- zero-init h state ----
    {
        unsigned short* ph = (unsigned short*)sh_h;
        for (int i = tid; i < 2 * 16 * HS; i += 512) ph[i] = 0;
    }
    __syncthreads();

    const float2* xp = (const float2*)x + (size_t)(batch0 + n) * NT;
    float2 xv = xp[0];
    float ctilm = 0.0f;   // -2*log2e * c
    float* outB = out + (size_t)batch0 * NT;

    // head for time base+wid from chunk buffer `buf`
#define HEAD(buf, base)                                                        \
    {                                                                          \
        const bf16x8 bth = ld_frag4(&sh_t[buf][wid][n][8 * g]);                \
        f32x4 hacc;                                                            \
        _Pragma("unroll")                                                      \
        for (int r = 0; r < 4; ++r) hacc[r] = b1r[r];                          \
        hacc = __builtin_amdgcn_mfma_f32_16x16x32_bf16(w1hi, bth, hacc, 0,0,0);\
        hacc = __builtin_amdgcn_mfma_f32_16x16x32_bf16(w1lo, bth, hacc, 0,0,0);\
        float p = 0.0f;                                                        \
        _Pragma("unroll")                                                      \
        for (int r = 0; r < 4; ++r) p += ftanh(hacc[r]) * w2r[r];              \
        p += __shfl_xor(p, 16);                                                \
        p += __shfl_xor(p, 32);                                                \
        if (g == 0) outB[(size_t)n * NT + ((base) + wid)] = p + b2v;           \
    }

    int cur = 0;
    for (int t = 0; t < NT; ++t) {
        // ---- critical chain: read h(t-1), MFMA, activations, write h(t) ----
        const bf16x8 bh = ld_frag4(&sh_h[cur][n][8 * g]);

        f32x4 acc;   // C init = neg-scaled biases + neg-scaled W_ih * x_t
#pragma unroll
        for (int r = 0; r < 4; ++r)
            acc[r] = fmaf(xv.x, wihx[r], fmaf(xv.y, wihy[r], bias[r]));

        acc = __builtin_amdgcn_mfma_f32_16x16x32_bf16(afrag, bh, acc, 0, 0, 0);

        const float2 xn = xp[(t + 1 < NT) ? t + 1 : t];   // prefetch

        // fused activations: acc[r] = -log2e*a_r (g-row: -2log2e*a_g)
        // -> every exp is a bare exp2; 5 exp2 + 3 rcp total
        const float p0 = ex2(acc[0]);              // e^-a_i
        const float p1 = ex2(acc[1]);              // e^-a_f
        const float q2 = ex2(acc[2]);              // e^-2a_g
        const float p3 = ex2(acc[3]);              // e^-a_o
        const float igg = (1.0f - q2) * frcp((1.0f + p0) * (1.0f + q2)); // i*g
        const float fg  = frcp(1.0f + p1);                               // f
        ctilm = fmaf(fg, ctilm, -L2E2 * igg);      // ctilm = -2log2e*c
        const float qc = ex2(ctilm);               // e^-2c
        const float hk = (1.0f - qc) * frcp((1.0f + p3) * (1.0f + qc));  // o*tanh(c)

        const int nxt = cur ^ 1;
        sh_h[nxt][n][j] = (unsigned short)cvt_pk_bf16(hk, hk);   // h bf16
        __syncthreads();   // h(t) visible; thk/head run in next read's shadow

        // ---- post-barrier (off the recurrence chain) ----
        const int tb = (t >> 3) & 1;
        const float thk = ftanh(hk);
        sh_t[tb][t & 7][n][j] = (unsigned short)cvt_pk_bf16(thk, thk);

        if ((t & 7) == 7 && t != 7)
            HEAD(tb ^ 1, t - 15)    // times t-15 .. t-8 (previous chunk)

        xv = xn;
        cur = nxt;
    }

    // epilogue: last chunk (times 504..511, buffer 1)
    __syncthreads();
    HEAD(1, NT - 8)
#undef HEAD
}

extern "C" void kernel_launch(void* const* d_in, const int* in_sizes, int n_in,
                              void* d_out, int out_size, void* d_ws, size_t ws_size,
                              hipStream_t stream) {
    const float* x    = (const float*)d_in[0];
    const float* W_ih = (const float*)d_in[1];
    const float* W_hh = (const float*)d_in[2];
    const float* b_ih = (const float*)d_in[3];
    const float* b_hh = (const float*)d_in[4];
    const float* W1   = (const float*)d_in[5];
    const float* b1   = (const float*)d_in[6];
    const float* W2   = (const float*)d_in[7];
    const float* b2   = (const float*)d_in[8];
    float* out = (float*)d_out;

    lstm_mfma_kernel<<<dim3(NB / 16), dim3(512), 0, stream>>>(
        x, W_ih, W_hh, b_ih, b_hh, W1, b1, W2, b2, out);
}

// Round 13
// 189.914 us; speedup vs baseline: 1.0539x; 1.0539x over previous
//
#include <hip/hip_runtime.h>

#define NB 4096
#define NT 512
#define HS 40   // ushort stride per batch row (80 B: 16B-aligned, 2-way banks = free)

typedef float f32x4 __attribute__((ext_vector_type(4)));
typedef short bf16x8 __attribute__((ext_vector_type(8)));

#define L2E  1.4426950408889634f   // log2(e)
#define L2E2 2.8853900817779268f   // 2*log2(e)

// ocml native exp2 -> single v_exp_f32, compiler-visible (no inline asm)
extern "C" __device__ float __ocml_native_exp2_f32(float);
__device__ __forceinline__ float ex2(float x) { return __ocml_native_exp2_f32(x); }

__device__ __forceinline__ float frcp(float x) { return __builtin_amdgcn_rcpf(x); }
__device__ __forceinline__ float ftanh(float x) {   // off-chain users only
    return 2.0f * frcp(1.0f + __expf(-2.0f * x)) - 1.0f;
}
// one inst packs two f32->bf16 (RTNE): result = [bf16(a) | bf16(b)<<16]
__device__ __forceinline__ unsigned cvt_pk_bf16(float a, float b) {
    unsigned r;
    asm("v_cvt_pk_bf16_f32 %0, %1, %2" : "=v"(r) : "v"(a), "v"(b));
    return r;
}
// RTNE f32->bf16 (prologue / weight prep only)
__device__ __forceinline__ unsigned short f2bf(float f) {
    unsigned u = __builtin_bit_cast(unsigned, f);
    u += 0x7fffu + ((u >> 16) & 1u);
    return (unsigned short)(u >> 16);
}
__device__ __forceinline__ float bf2f(unsigned short h) {
    return __builtin_bit_cast(float, (unsigned)h << 16);
}

// 256 blocks x 8 waves x 16 batches. Per step, wave w computes its 16-row
// gate tile with ONE mfma_f32_16x16x32_bf16 (A = permuted W_hh, B = h bf16);
// C/D layout (col=lane&15=batch n, row-group=lane>>4=g) gives each lane all
// 4 gates of hidden j=4*wid+g -> activations in-register, one barrier/step.
// Gate rows are prescaled by -log2e (-2log2e for the g-gate row) at weight
// load, so every activation exp is a BARE exp2: p_r = 2^(acc_r) = e^(-a_r);
// c is carried negated-scaled as ctilm = -2log2e*c. Chain per step:
// bar -> ds_read_b128 -> MFMA -> 5 exp2 + 3 rcp fused acts -> b16 write ->
// bar. tanh(h), sh_t write and the chunked head (hi/lo W1 MFMA pair per 8
// steps) run post-barrier in the next step's read/MFMA shadow.
__global__ __launch_bounds__(512, 2) void lstm_mfma_kernel(
    const float* __restrict__ x,
    const float* __restrict__ W_ih,
    const float* __restrict__ W_hh,
    const float* __restrict__ b_ih,
    const float* __restrict__ b_hh,
    const float* __restrict__ W1,
    const float* __restrict__ b1,
    const float* __restrict__ W2,
    const float* __restrict__ b2,
    float* __restrict__ out)
{
    const int tid  = threadIdx.x;
    const int wid  = tid >> 6;
    const int lane = tid & 63;
    const int g    = lane >> 4;     // row-group (C rows 4g..4g+3) / B k-slice
    const int n    = lane & 15;     // batch column
    const int j    = 4 * wid + g;   // hidden unit owned by this lane
    const int batch0 = blockIdx.x * 16;

    __shared__ __align__(16) unsigned short sh_h[2][16][HS];    // h bf16 [buf][n][j]
    __shared__ __align__(16) unsigned short sh_t[2][8][16][HS]; // tanh(h) [buf][tc][n][j]

    // ---- gate A fragment: lane holds row m=lane&15, k = 8g..8g+7 of the
    //      permuted W_hh tile (row m -> gate (m&3), hidden 4*wid+(m>>2)),
    //      prescaled by -log2e (g-gate row: -2log2e) ----
    bf16x8 afrag;
    {
        const int m = lane & 15;
        const float nsc = ((m & 3) == 2) ? -L2E2 : -L2E;
        const int grow = (m & 3) * 32 + 4 * wid + (m >> 2);
        const float* wp = W_hh + grow * 32 + 8 * g;
#pragma unroll
        for (int i = 0; i < 8; ++i) afrag[i] = (short)f2bf(wp[i] * nsc);
    }

    // ---- per-lane gate params for hidden j: rows r*32+j, prescaled ----
    float wihx[4], wihy[4], bias[4];
#pragma unroll
    for (int r = 0; r < 4; ++r) {
        const float nsc = (r == 2) ? -L2E2 : -L2E;
        const int row = r * 32 + j;
        wihx[r] = W_ih[row * 2 + 0] * nsc;
        wihy[r] = W_ih[row * 2 + 1] * nsc;
        bias[r] = (b_ih[row] + b_hh[row]) * nsc;
    }

    // ---- head A fragment: W1 rows m=lane&15, split bf16 hi+lo (unscaled) ----
    bf16x8 w1hi, w1lo;
    {
        const float* wp = W1 + (lane & 15) * 32 + 8 * g;
#pragma unroll
        for (int i = 0; i < 8; ++i) {
            const float w = wp[i];
            const unsigned short hi = f2bf(w);
            w1hi[i] = (short)hi;
            w1lo[i] = (short)f2bf(w - bf2f(hi));
        }
    }
    float b1r[4], w2r[4];   // fc1 output d = 4g+r
#pragma unroll
    for (int r = 0; r < 4; ++r) {
        b1r[r] = b1[4 * g + r];
        w2r[r] = W2[4 * g + r];
    }
    const float b2v = b2[0];

    // ---- zero-init h state ----
    {
        unsigned short* ph = (unsigned short*)sh_h;
        for (int i = tid; i < 2 * 16 * HS; i += 512) ph[i] = 0;
    }
    __syncthreads();

    const float2* xp = (const float2*)x + (size_t)(batch0 + n) * NT;
    float2 xv = xp[0];
    float ctilm = 0.0f;   // -2*log2e * c
    float* outB = out + (size_t)batch0 * NT;

    // head for time base+wid from chunk buffer `buf`
#define HEAD(buf, base)                                                        \
    {                                                                          \
        const bf16x8 bth = *(const bf16x8*)&sh_t[buf][wid][n][8 * g];          \
        f32x4 hacc;                                                            \
        _Pragma("unroll")                                                      \
        for (int r = 0; r < 4; ++r) hacc[r] = b1r[r];                          \
        hacc = __builtin_amdgcn_mfma_f32_16x16x32_bf16(w1hi, bth, hacc, 0,0,0);\
        hacc = __builtin_amdgcn_mfma_f32_16x16x32_bf16(w1lo, bth, hacc, 0,0,0);\
        float p = 0.0f;                                                        \
        _Pragma("unroll")                                                      \
        for (int r = 0; r < 4; ++r) p += ftanh(hacc[r]) * w2r[r];              \
        p += __shfl_xor(p, 16);                                                \
        p += __shfl_xor(p, 32);                                                \
        if (g == 0) outB[(size_t)n * NT + ((base) + wid)] = p + b2v;           \
    }

    int cur = 0;
    for (int t = 0; t < NT; ++t) {
        // ---- critical chain: read h(t-1), MFMA, activations, write h(t) ----
        const bf16x8 bh = *(const bf16x8*)&sh_h[cur][n][8 * g];

        f32x4 acc;   // C init = neg-scaled biases + neg-scaled W_ih * x_t
#pragma unroll
        for (int r = 0; r < 4; ++r)
            acc[r] = fmaf(xv.x, wihx[r], fmaf(xv.y, wihy[r], bias[r]));

        acc = __builtin_amdgcn_mfma_f32_16x16x32_bf16(afrag, bh, acc, 0, 0, 0);

        const float2 xn = xp[(t + 1 < NT) ? t + 1 : t];   // prefetch

        // fused activations: acc[r] = -log2e*a_r (g-row: -2log2e*a_g)
        // -> every exp is a bare exp2; 5 exp2 + 3 rcp total
        const float p0 = ex2(acc[0]);              // e^-a_i
        const float p1 = ex2(acc[1]);              // e^-a_f
        const float q2 = ex2(acc[2]);              // e^-2a_g
        const float p3 = ex2(acc[3]);              // e^-a_o
        const float igg = (1.0f - q2) * frcp((1.0f + p0) * (1.0f + q2)); // i*g
        const float fg  = frcp(1.0f + p1);                               // f
        ctilm = fmaf(fg, ctilm, -L2E2 * igg);      // ctilm = -2log2e*c
        const float qc = ex2(ctilm);               // e^-2c
        const float hk = (1.0f - qc) * frcp((1.0f + p3) * (1.0f + qc));  // o*tanh(c)

        const int nxt = cur ^ 1;
        sh_h[nxt][n][j] = (unsigned short)cvt_pk_bf16(hk, hk);   // h bf16
        __syncthreads();   // h(t) visible; thk/head run in next read's shadow

        // ---- post-barrier (off the recurrence chain) ----
        const int tb = (t >> 3) & 1;
        const float thk = ftanh(hk);
        sh_t[tb][t & 7][n][j] = (unsigned short)cvt_pk_bf16(thk, thk);

        if ((t & 7) == 7 && t != 7)
            HEAD(tb ^ 1, t - 15)    // times t-15 .. t-8 (previous chunk)

        xv = xn;
        cur = nxt;
    }

    // epilogue: last chunk (times 504..511, buffer 1)
    __syncthreads();
    HEAD(1, NT - 8)
#undef HEAD
}

extern "C" void kernel_launch(void* const* d_in, const int* in_sizes, int n_in,
                              void* d_out, int out_size, void* d_ws, size_t ws_size,
                              hipStream_t stream) {
    const float* x    = (const float*)d_in[0];
    const float* W_ih = (const float*)d_in[1];
    const float* W_hh = (const float*)d_in[2];
    const float* b_ih = (const float*)d_in[3];
    const float* b_hh = (const float*)d_in[4];
    const float* W1   = (const float*)d_in[5];
    const float* b1   = (const float*)d_in[6];
    const float* W2   = (const float*)d_in[7];
    const float* b2   = (const float*)d_in[8];
    float* out = (float*)d_out;

    lstm_mfma_kernel<<<dim3(NB / 16), dim3(512), 0, stream>>>(
        x, W_ih, W_hh, b_ih, b_hh, W1, b1, W2, b2, out);
}

// Round 14
// 167.139 us; speedup vs baseline: 1.1975x; 1.1363x over previous
//
#include <hip/hip_runtime.h>

#define NB 4096
#define NT 512
#define HS 40   // ushort stride per batch row (80 B: 16B-aligned, 2-way banks = free)

typedef float f32x4 __attribute__((ext_vector_type(4)));
typedef short bf16x8 __attribute__((ext_vector_type(8)));

#define L2E  1.4426950408889634f   // log2(e)
#define L2E2 2.8853900817779268f   // 2*log2(e)

// ocml native exp2 -> single v_exp_f32, compiler-visible (no inline asm)
extern "C" __device__ float __ocml_native_exp2_f32(float);
__device__ __forceinline__ float ex2(float x) { return __ocml_native_exp2_f32(x); }

__device__ __forceinline__ float frcp(float x) { return __builtin_amdgcn_rcpf(x); }
__device__ __forceinline__ float ftanh(float x) {   // off-chain users only
    return 2.0f * frcp(1.0f + __expf(-2.0f * x)) - 1.0f;
}
// one inst packs two f32->bf16 (RTNE): result = [bf16(a) | bf16(b)<<16]
__device__ __forceinline__ unsigned cvt_pk_bf16(float a, float b) {
    unsigned r;
    asm("v_cvt_pk_bf16_f32 %0, %1, %2" : "=v"(r) : "v"(a), "v"(b));
    return r;
}
// RTNE f32->bf16 (prologue / weight prep only)
__device__ __forceinline__ unsigned short f2bf(float f) {
    unsigned u = __builtin_bit_cast(unsigned, f);
    u += 0x7fffu + ((u >> 16) & 1u);
    return (unsigned short)(u >> 16);
}
__device__ __forceinline__ float bf2f(unsigned short h) {
    return __builtin_bit_cast(float, (unsigned)h << 16);
}

// 256 blocks x 8 waves x 16 batches (R13 structure). Per step, wave w
// computes its 16-row gate tile with ONE mfma_f32_16x16x32_bf16 (A = permuted
// W_hh prescaled by -log2e / -2log2e, B = h bf16); C/D layout
// (col=lane&15=batch n, row-group=lane>>4=g) gives each lane all 4 gates of
// hidden j=4*wid+g -> activations in-register, one barrier/step; every exp is
// a bare exp2 (ctilm = -2log2e*c). x is loaded in 4-STEP REGISTER CHUNKS (two
// float4 issued as the first insts of every 4th step): 3 of 4 end-of-step
// barrier vmcnt(0) drains have zero outstanding VMEM, the 4th has max shadow.
// tanh(h), sh_t write and the chunked head (hi/lo W1 MFMA pair per 8 steps)
// run post-barrier in the next step's read/MFMA shadow.
__global__ __launch_bounds__(512, 2) void lstm_mfma_kernel(
    const float* __restrict__ x,
    const float* __restrict__ W_ih,
    const float* __restrict__ W_hh,
    const float* __restrict__ b_ih,
    const float* __restrict__ b_hh,
    const float* __restrict__ W1,
    const float* __restrict__ b1,
    const float* __restrict__ W2,
    const float* __restrict__ b2,
    float* __restrict__ out)
{
    const int tid  = threadIdx.x;
    const int wid  = tid >> 6;
    const int lane = tid & 63;
    const int g    = lane >> 4;     // row-group (C rows 4g..4g+3) / B k-slice
    const int n    = lane & 15;     // batch column
    const int j    = 4 * wid + g;   // hidden unit owned by this lane
    const int batch0 = blockIdx.x * 16;

    __shared__ __align__(16) unsigned short sh_h[2][16][HS];    // h bf16 [buf][n][j]
    __shared__ __align__(16) unsigned short sh_t[2][8][16][HS]; // tanh(h) [buf][tc][n][j]

    // ---- gate A fragment: lane holds row m=lane&15, k = 8g..8g+7 of the
    //      permuted W_hh tile (row m -> gate (m&3), hidden 4*wid+(m>>2)),
    //      prescaled by -log2e (g-gate row: -2log2e) ----
    bf16x8 afrag;
    {
        const int m = lane & 15;
        const float nsc = ((m & 3) == 2) ? -L2E2 : -L2E;
        const int grow = (m & 3) * 32 + 4 * wid + (m >> 2);
        const float* wp = W_hh + grow * 32 + 8 * g;
#pragma unroll
        for (int i = 0; i < 8; ++i) afrag[i] = (short)f2bf(wp[i] * nsc);
    }

    // ---- per-lane gate params for hidden j: rows r*32+j, prescaled ----
    float wihx[4], wihy[4], bias[4];
#pragma unroll
    for (int r = 0; r < 4; ++r) {
        const float nsc = (r == 2) ? -L2E2 : -L2E;
        const int row = r * 32 + j;
        wihx[r] = W_ih[row * 2 + 0] * nsc;
        wihy[r] = W_ih[row * 2 + 1] * nsc;
        bias[r] = (b_ih[row] + b_hh[row]) * nsc;
    }

    // ---- head A fragment: W1 rows m=lane&15, split bf16 hi+lo (unscaled) ----
    bf16x8 w1hi, w1lo;
    {
        const float* wp = W1 + (lane & 15) * 32 + 8 * g;
#pragma unroll
        for (int i = 0; i < 8; ++i) {
            const float w = wp[i];
            const unsigned short hi = f2bf(w);
            w1hi[i] = (short)hi;
            w1lo[i] = (short)f2bf(w - bf2f(hi));
        }
    }
    float b1r[4], w2r[4];   // fc1 output d = 4g+r
#pragma unroll
    for (int r = 0; r < 4; ++r) {
        b1r[r] = b1[4 * g + r];
        w2r[r] = W2[4 * g + r];
    }
    const float b2v = b2[0];

    // ---- zero-init h state ----
    {
        unsigned short* ph = (unsigned short*)sh_h;
        for (int i = tid; i < 2 * 16 * HS; i += 512) ph[i] = 0;
    }
    __syncthreads();

    // x in 4-step register chunks: chunk c covers t = 4c..4c+3 (32 B aligned)
    const float4* xq = (const float4*)(x + (size_t)(batch0 + n) * (NT * 2));
    float4 xa = xq[0], xb = xq[1];   // current chunk
    float4 na, nb;                   // next chunk (loaded at s==0)
    float ctilm = 0.0f;              // -2*log2e * c
    float* outB = out + (size_t)batch0 * NT;

    // head for time base+wid from chunk buffer `buf`
#define HEAD(buf, base)                                                        \
    {                                                                          \
        const bf16x8 bth = *(const bf16x8*)&sh_t[buf][wid][n][8 * g];          \
        f32x4 hacc;                                                            \
        _Pragma("unroll")                                                      \
        for (int r = 0; r < 4; ++r) hacc[r] = b1r[r];                          \
        hacc = __builtin_amdgcn_mfma_f32_16x16x32_bf16(w1hi, bth, hacc, 0,0,0);\
        hacc = __builtin_amdgcn_mfma_f32_16x16x32_bf16(w1lo, bth, hacc, 0,0,0);\
        float p = 0.0f;                                                        \
        _Pragma("unroll")                                                      \
        for (int r = 0; r < 4; ++r) p += ftanh(hacc[r]) * w2r[r];              \
        p += __shfl_xor(p, 16);                                                \
        p += __shfl_xor(p, 32);                                                \
        if (g == 0) outB[(size_t)n * NT + ((base) + wid)] = p + b2v;           \
    }

    int cur = 0;
    for (int t4 = 0; t4 < NT; t4 += 4) {
#pragma unroll
        for (int s = 0; s < 4; ++s) {
            const int t = t4 + s;

            // issue next-chunk loads FIRST (max shadow before vmcnt drain)
            if (s == 0) {
                const int c2 = (t4 + 4 < NT) ? (t4 / 4 + 1) * 2 : (t4 / 4) * 2;
                na = xq[c2];
                nb = xq[c2 + 1];
            }
            const float2 xv = (s == 0) ? make_float2(xa.x, xa.y)
                            : (s == 1) ? make_float2(xa.z, xa.w)
                            : (s == 2) ? make_float2(xb.x, xb.y)
                                       : make_float2(xb.z, xb.w);

            // ---- critical chain: read h(t-1), MFMA, acts, write h(t) ----
            const bf16x8 bh = *(const bf16x8*)&sh_h[cur][n][8 * g];

            f32x4 acc;   // C init = neg-scaled biases + neg-scaled W_ih * x_t
#pragma unroll
            for (int r = 0; r < 4; ++r)
                acc[r] = fmaf(xv.x, wihx[r], fmaf(xv.y, wihy[r], bias[r]));

            acc = __builtin_amdgcn_mfma_f32_16x16x32_bf16(afrag, bh, acc, 0, 0, 0);

            // fused activations: acc[r] = -log2e*a_r (g-row: -2log2e*a_g)
            const float p0 = ex2(acc[0]);              // e^-a_i
            const float p1 = ex2(acc[1]);              // e^-a_f
            const float q2 = ex2(acc[2]);              // e^-2a_g
            const float p3 = ex2(acc[3]);              // e^-a_o
            const float igg = (1.0f - q2) * frcp((1.0f + p0) * (1.0f + q2));
            const float fg  = frcp(1.0f + p1);
            ctilm = fmaf(fg, ctilm, -L2E2 * igg);      // ctilm = -2log2e*c
            const float qc = ex2(ctilm);               // e^-2c
            const float hk = (1.0f - qc) * frcp((1.0f + p3) * (1.0f + qc));

            const int nxt = cur ^ 1;
            sh_h[nxt][n][j] = (unsigned short)cvt_pk_bf16(hk, hk);   // h bf16
            __syncthreads();   // h(t) visible; thk/head run in next read's shadow

            // ---- post-barrier (off the recurrence chain) ----
            const int tb = (t >> 3) & 1;
            const float thk = ftanh(hk);
            sh_t[tb][t & 7][n][j] = (unsigned short)cvt_pk_bf16(thk, thk);

            if ((t & 7) == 7 && t != 7)
                HEAD(tb ^ 1, t - 15)    // times t-15 .. t-8 (previous chunk)

            if (s == 3) { xa = na; xb = nb; }
            cur = nxt;
        }
    }

    // epilogue: last chunk (times 504..511, buffer 1)
    __syncthreads();
    HEAD(1, NT - 8)
#undef HEAD
}

extern "C" void kernel_launch(void* const* d_in, const int* in_sizes, int n_in,
                              void* d_out, int out_size, void* d_ws, size_t ws_size,
                              hipStream_t stream) {
    const float* x    = (const float*)d_in[0];
    const float* W_ih = (const float*)d_in[1];
    const float* W_hh = (const float*)d_in[2];
    const float* b_ih = (const float*)d_in[3];
    const float* b_hh = (const float*)d_in[4];
    const float* W1   = (const float*)d_in[5];
    const float* b1   = (const float*)d_in[6];
    const float* W2   = (const float*)d_in[7];
    const float* b2   = (const float*)d_in[8];
    float* out = (float*)d_out;

    lstm_mfma_kernel<<<dim3(NB / 16), dim3(512), 0, stream>>>(
        x, W_ih, W_hh, b_ih, b_hh, W1, b1, W2, b2, out);
}

// Round 15
// 165.741 us; speedup vs baseline: 1.2076x; 1.0084x over previous
//
#include <hip/hip_runtime.h>

#define NB 4096
#define NT 512
#define HS 40    // ushort stride per batch row (80 B: 16B-aligned, 2-way banks = free)
#define XS 513   // float2 stride per x row (4104 B): dword banks (2n+2t)%32
                 // distinct across the 16 batch rows -> conflict-free ds_read_b64

typedef float f32x4 __attribute__((ext_vector_type(4)));
typedef short bf16x8 __attribute__((ext_vector_type(8)));

#define L2E  1.4426950408889634f   // log2(e)
#define L2E2 2.8853900817779268f   // 2*log2(e)

// ocml native exp2 -> single v_exp_f32, compiler-visible (no inline asm)
extern "C" __device__ float __ocml_native_exp2_f32(float);
__device__ __forceinline__ float ex2(float x) { return __ocml_native_exp2_f32(x); }

__device__ __forceinline__ float frcp(float x) { return __builtin_amdgcn_rcpf(x); }
__device__ __forceinline__ float ftanh(float x) {   // off-chain users only
    return 2.0f * frcp(1.0f + __expf(-2.0f * x)) - 1.0f;
}
// one inst packs two f32->bf16 (RTNE): result = [bf16(a) | bf16(b)<<16]
__device__ __forceinline__ unsigned cvt_pk_bf16(float a, float b) {
    unsigned r;
    asm("v_cvt_pk_bf16_f32 %0, %1, %2" : "=v"(r) : "v"(a), "v"(b));
    return r;
}
// RTNE f32->bf16 (prologue / weight prep only)
__device__ __forceinline__ unsigned short f2bf(float f) {
    unsigned u = __builtin_bit_cast(unsigned, f);
    u += 0x7fffu + ((u >> 16) & 1u);
    return (unsigned short)(u >> 16);
}
__device__ __forceinline__ float bf2f(unsigned short h) {
    return __builtin_bit_cast(float, (unsigned)h << 16);
}

// 256 blocks x 8 waves x 16 batches (R13/R14 structure). Per step, wave w
// computes its 16-row gate tile with ONE mfma_f32_16x16x32_bf16 (A = permuted
// W_hh prescaled by -log2e / -2log2e, B = h bf16); C/D layout
// (col=lane&15=batch n, row-group=lane>>4=g) gives each lane all 4 gates of
// hidden j=4*wid+g -> activations in-register, one barrier/step; every exp
// is a bare exp2 (ctilm = -2log2e*c). The block's x slice (16 consecutive
// batches x 4KB = 64KB contiguous) is STAGED ENTIRELY INTO LDS in the
// prologue -> the steady loop issues ZERO global loads, so every per-step
// barrier's vmcnt(0) drain is free (only the HEAD store every 8th step is
// outstanding, with a full step of shadow). x reads are ds_read_b64,
// overlapped with the h-fragment read. tanh(h), sh_t write and the chunked
// head (hi/lo W1 MFMA pair per 8 steps) run post-barrier.
__global__ __launch_bounds__(512, 2) void lstm_mfma_kernel(
    const float* __restrict__ x,
    const float* __restrict__ W_ih,
    const float* __restrict__ W_hh,
    const float* __restrict__ b_ih,
    const float* __restrict__ b_hh,
    const float* __restrict__ W1,
    const float* __restrict__ b1,
    const float* __restrict__ W2,
    const float* __restrict__ b2,
    float* __restrict__ out)
{
    const int tid  = threadIdx.x;
    const int wid  = tid >> 6;
    const int lane = tid & 63;
    const int g    = lane >> 4;     // row-group (C rows 4g..4g+3) / B k-slice
    const int n    = lane & 15;     // batch column
    const int j    = 4 * wid + g;   // hidden unit owned by this lane
    const int batch0 = blockIdx.x * 16;

    __shared__ __align__(16) float2 sh_x[16][XS];               // x slice, 64.1 KB
    __shared__ __align__(16) unsigned short sh_h[2][16][HS];    // h bf16 [buf][n][j]
    __shared__ __align__(16) unsigned short sh_t[2][8][16][HS]; // tanh(h) [buf][tc][n][j]

    // ---- stage x[batch0..batch0+15] into LDS (contiguous 64KB, coalesced;
    //      dest rows padded to XS) ----
    {
        const float4* xg = (const float4*)(x + (size_t)batch0 * (NT * 2));
        char* xbase = (char*)&sh_x[0][0];
#pragma unroll
        for (int k = 0; k < 8; ++k) {
            const int f = tid + k * 512;        // float4 index, 0..4095
            const float4 v = xg[f];
            const int nn = f >> 8;              // batch row
            const int q  = f & 255;             // float4 within row
            *(float4*)(xbase + (size_t)nn * (XS * 8) + (size_t)q * 16) = v;
        }
    }

    // ---- gate A fragment: lane holds row m=lane&15, k = 8g..8g+7 of the
    //      permuted W_hh tile (row m -> gate (m&3), hidden 4*wid+(m>>2)),
    //      prescaled by -log2e (g-gate row: -2log2e) ----
    bf16x8 afrag;
    {
        const int m = lane & 15;
        const float nsc = ((m & 3) == 2) ? -L2E2 : -L2E;
        const int grow = (m & 3) * 32 + 4 * wid + (m >> 2);
        const float* wp = W_hh + grow * 32 + 8 * g;
#pragma unroll
        for (int i = 0; i < 8; ++i) afrag[i] = (short)f2bf(wp[i] * nsc);
    }

    // ---- per-lane gate params for hidden j: rows r*32+j, prescaled ----
    float wihx[4], wihy[4], bias[4];
#pragma unroll
    for (int r = 0; r < 4; ++r) {
        const float nsc = (r == 2) ? -L2E2 : -L2E;
        const int row = r * 32 + j;
        wihx[r] = W_ih[row * 2 + 0] * nsc;
        wihy[r] = W_ih[row * 2 + 1] * nsc;
        bias[r] = (b_ih[row] + b_hh[row]) * nsc;
    }

    // ---- head A fragment: W1 rows m=lane&15, split bf16 hi+lo (unscaled) ----
    bf16x8 w1hi, w1lo;
    {
        const float* wp = W1 + (lane & 15) * 32 + 8 * g;
#pragma unroll
        for (int i = 0; i < 8; ++i) {
            const float w = wp[i];
            const unsigned short hi = f2bf(w);
            w1hi[i] = (short)hi;
            w1lo[i] = (short)f2bf(w - bf2f(hi));
        }
    }
    float b1r[4], w2r[4];   // fc1 output d = 4g+r
#pragma unroll
    for (int r = 0; r < 4; ++r) {
        b1r[r] = b1[4 * g + r];
        w2r[r] = W2[4 * g + r];
    }
    const float b2v = b2[0];

    // ---- zero-init h state ----
    {
        unsigned short* ph = (unsigned short*)sh_h;
        for (int i = tid; i < 2 * 16 * HS; i += 512) ph[i] = 0;
    }
    __syncthreads();   // x staged + h zeroed

    float ctilm = 0.0f;   // -2*log2e * c
    float* outB = out + (size_t)batch0 * NT;

    // head for time base+wid from chunk buffer `buf`
#define HEAD(buf, base)                                                        \
    {                                                                          \
        const bf16x8 bth = *(const bf16x8*)&sh_t[buf][wid][n][8 * g];          \
        f32x4 hacc;                                                            \
        _Pragma("unroll")                                                      \
        for (int r = 0; r < 4; ++r) hacc[r] = b1r[r];                          \
        hacc = __builtin_amdgcn_mfma_f32_16x16x32_bf16(w1hi, bth, hacc, 0,0,0);\
        hacc = __builtin_amdgcn_mfma_f32_16x16x32_bf16(w1lo, bth, hacc, 0,0,0);\
        float p = 0.0f;                                                        \
        _Pragma("unroll")                                                      \
        for (int r = 0; r < 4; ++r) p += ftanh(hacc[r]) * w2r[r];              \
        p += __shfl_xor(p, 16);                                                \
        p += __shfl_xor(p, 32);                                                \
        if (g == 0) outB[(size_t)n * NT + ((base) + wid)] = p + b2v;           \
    }

    int cur = 0;
    for (int t = 0; t < NT; ++t) {
        // ---- critical chain: read h(t-1) (+x from LDS, overlapped), MFMA,
        //      acts, write h(t) ----
        const bf16x8 bh = *(const bf16x8*)&sh_h[cur][n][8 * g];
        const float2 xv = sh_x[n][t];   // broadcast across g, conflict-free

        f32x4 acc;   // C init = neg-scaled biases + neg-scaled W_ih * x_t
#pragma unroll
        for (int r = 0; r < 4; ++r)
            acc[r] = fmaf(xv.x, wihx[r], fmaf(xv.y, wihy[r], bias[r]));

        acc = __builtin_amdgcn_mfma_f32_16x16x32_bf16(afrag, bh, acc, 0, 0, 0);

        // fused activations: acc[r] = -log2e*a_r (g-row: -2log2e*a_g)
        // -> every exp is a bare exp2; 5 exp2 + 3 rcp total
        const float p0 = ex2(acc[0]);              // e^-a_i
        const float p1 = ex2(acc[1]);              // e^-a_f
        const float q2 = ex2(acc[2]);              // e^-2a_g
        const float p3 = ex2(acc[3]);              // e^-a_o
        const float igg = (1.0f - q2) * frcp((1.0f + p0) * (1.0f + q2)); // i*g
        const float fg  = frcp(1.0f + p1);                               // f
        ctilm = fmaf(fg, ctilm, -L2E2 * igg);      // ctilm = -2log2e*c
        const float qc = ex2(ctilm);               // e^-2c
        const float hk = (1.0f - qc) * frcp((1.0f + p3) * (1.0f + qc));  // o*tanh(c)

        const int nxt = cur ^ 1;
        sh_h[nxt][n][j] = (unsigned short)cvt_pk_bf16(hk, hk);   // h bf16
        __syncthreads();   // h(t) visible; thk/head run in next read's shadow

        // ---- post-barrier (off the recurrence chain) ----
        const int tb = (t >> 3) & 1;
        const float thk = ftanh(hk);
        sh_t[tb][t & 7][n][j] = (unsigned short)cvt_pk_bf16(thk, thk);

        if ((t & 7) == 7 && t != 7)
            HEAD(tb ^ 1, t - 15)    // times t-15 .. t-8 (previous chunk)

        cur = nxt;
    }

    // epilogue: last chunk (times 504..511, buffer 1)
    __syncthreads();
    HEAD(1, NT - 8)
#undef HEAD
}

extern "C" void kernel_launch(void* const* d_in, const int* in_sizes, int n_in,
                              void* d_out, int out_size, void* d_ws, size_t ws_size,
                              hipStream_t stream) {
    const float* x    = (const float*)d_in[0];
    const float* W_ih = (const float*)d_in[1];
    const float* W_hh = (const float*)d_in[2];
    const float* b_ih = (const float*)d_in[3];
    const float* b_hh = (const float*)d_in[4];
    const float* W1   = (const float*)d_in[5];
    const float* b1   = (const float*)d_in[6];
    const float* W2   = (const float*)d_in[7];
    const float* b2   = (const float*)d_in[8];
    float* out = (float*)d_out;

    lstm_mfma_kernel<<<dim3(NB / 16), dim3(512), 0, stream>>>(
        x, W_ih, W_hh, b_ih, b_hh, W1, b1, W2, b2, out);
}